// Round 1
// baseline (858.290 us; speedup 1.0000x reference)
//
#include <hip/hip_runtime.h>
#include <hip/hip_bf16.h>

// ---------------------------------------------------------------------------
// GraphTransformerEncoder: 2x TransformerConv(beta=True) + LN(+ReLU) + pool
// Round 0: correctness-first f32 baseline.
//   - GEMMs (q,k,v,r per layer): f32 LDS-tiled 64x64x16
//   - CSR build on device (hist -> scan -> fill)
//   - Fused per-dst attention: one wave per node, online softmax (no max sub;
//     logits are tiny), beta gate + layernorm(+relu) fused in epilogue
//   - Global mean pool: sorted-batch chunked reduction + atomics on flush
// ---------------------------------------------------------------------------

#define DEVFN static __device__ __forceinline__

// ------------------------- GEMM: O[z] = A @ W[z] + b[z] ---------------------
// A: [M,256] row-major, W: [256,256] row-major, O: [M,256]
__global__ __launch_bounds__(256)
void gemm4_kernel(const float* __restrict__ A, int M,
                  const float* __restrict__ W0, const float* __restrict__ W1,
                  const float* __restrict__ W2, const float* __restrict__ W3,
                  const float* __restrict__ b0, const float* __restrict__ b1,
                  const float* __restrict__ b2, const float* __restrict__ b3,
                  float* __restrict__ O0, float* __restrict__ O1,
                  float* __restrict__ O2, float* __restrict__ O3)
{
    const float* W; const float* bias; float* O;
    switch (blockIdx.z) {
        case 0:  W = W0; bias = b0; O = O0; break;
        case 1:  W = W1; bias = b1; O = O1; break;
        case 2:  W = W2; bias = b2; O = O2; break;
        default: W = W3; bias = b3; O = O3; break;
    }

    __shared__ float As[64][17];   // +1 pad breaks 4-way bank conflict on tr
    __shared__ float Bs[16][64];

    const int tid  = threadIdx.x;
    const int row0 = blockIdx.x * 64;
    const int col0 = blockIdx.y * 64;
    const int tr   = tid >> 4;          // 0..15
    const int tc   = tid & 15;          // 0..15

    const int arow = tid >> 2;          // 0..63
    const int acol = (tid & 3) * 4;     // 0,4,8,12
    const int wrow = tid >> 4;          // 0..15
    const int wcol = (tid & 15) * 4;    // 0..60

    float c[4][4] = {};

    for (int k0 = 0; k0 < 256; k0 += 16) {
        float4 av = make_float4(0.f, 0.f, 0.f, 0.f);
        const int gr = row0 + arow;
        if (gr < M)
            av = *reinterpret_cast<const float4*>(A + (size_t)gr * 256 + k0 + acol);
        As[arow][acol + 0] = av.x;
        As[arow][acol + 1] = av.y;
        As[arow][acol + 2] = av.z;
        As[arow][acol + 3] = av.w;

        const float4 wv = *reinterpret_cast<const float4*>(
            W + (size_t)(k0 + wrow) * 256 + col0 + wcol);
        Bs[wrow][wcol + 0] = wv.x;
        Bs[wrow][wcol + 1] = wv.y;
        Bs[wrow][wcol + 2] = wv.z;
        Bs[wrow][wcol + 3] = wv.w;

        __syncthreads();

        #pragma unroll
        for (int kk = 0; kk < 16; ++kk) {
            float a[4], b[4];
            #pragma unroll
            for (int i = 0; i < 4; ++i) a[i] = As[tr * 4 + i][kk];
            #pragma unroll
            for (int j = 0; j < 4; ++j) b[j] = Bs[kk][tc * 4 + j];
            #pragma unroll
            for (int i = 0; i < 4; ++i)
                #pragma unroll
                for (int j = 0; j < 4; ++j)
                    c[i][j] = fmaf(a[i], b[j], c[i][j]);
        }
        __syncthreads();
    }

    const int col = col0 + tc * 4;
    const float4 bv = *reinterpret_cast<const float4*>(bias + col);
    #pragma unroll
    for (int i = 0; i < 4; ++i) {
        const int gr = row0 + tr * 4 + i;
        if (gr < M) {
            float4 ov;
            ov.x = c[i][0] + bv.x;
            ov.y = c[i][1] + bv.y;
            ov.z = c[i][2] + bv.z;
            ov.w = c[i][3] + bv.w;
            *reinterpret_cast<float4*>(O + (size_t)gr * 256 + col) = ov;
        }
    }
}

// ------------------------------ CSR build ----------------------------------
__global__ __launch_bounds__(256)
void hist_kernel(const int* __restrict__ ei, int E, int* __restrict__ deg)
{
    const int e = blockIdx.x * 256 + threadIdx.x;
    if (e < E) atomicAdd(&deg[ei[E + e]], 1);   // dst row
}

__global__ __launch_bounds__(256)
void gcount_kernel(const int* __restrict__ batch, int N, int* __restrict__ gcount)
{
    const int n = blockIdx.x * 256 + threadIdx.x;
    if (n < N) atomicAdd(&gcount[batch[n]], 1);
}

__global__ __launch_bounds__(1024)
void scan_kernel(const int* __restrict__ deg, int* __restrict__ row_start, int n)
{
    __shared__ int sh[1024];
    const int tid = threadIdx.x;
    if (tid == 0) row_start[0] = 0;
    int offset = 0;
    for (int base = 0; base < n; base += 1024) {
        const int idx = base + tid;
        sh[tid] = (idx < n) ? deg[idx] : 0;
        __syncthreads();
        #pragma unroll
        for (int d = 1; d < 1024; d <<= 1) {
            const int t = (tid >= d) ? sh[tid - d] : 0;
            __syncthreads();
            sh[tid] += t;
            __syncthreads();
        }
        if (idx < n) row_start[idx + 1] = offset + sh[tid];
        offset += sh[1023];
        __syncthreads();
    }
}

__global__ __launch_bounds__(256)
void fill_kernel(const int* __restrict__ ei, int E,
                 const int* __restrict__ row_start,
                 int* __restrict__ cursor, int* __restrict__ csr_src)
{
    const int e = blockIdx.x * 256 + threadIdx.x;
    if (e >= E) return;
    const int s = ei[e];
    const int d = ei[E + e];
    const int pos = atomicAdd(&cursor[d], 1);
    csr_src[row_start[d] + pos] = s;
}

// --------------------- fused attention + gate + layernorm ------------------
// One 64-lane wave per dst node. HL = lanes per head (16 for H=4/C=64,
// 64 for H=1/C=256). Lane l owns dims 4l..4l+3 (float4).
template <int HL, bool RELU>
__global__ __launch_bounds__(256)
void attn_kernel(const float* __restrict__ Q, const float* __restrict__ K,
                 const float* __restrict__ V, const float* __restrict__ R,
                 const float* __restrict__ Wb, const float* __restrict__ lng,
                 const float* __restrict__ lnb,
                 const int* __restrict__ row_start, const int* __restrict__ csr_src,
                 float* __restrict__ out, int N, float scale)
{
    const int wave = threadIdx.x >> 6;
    const int lane = threadIdx.x & 63;
    const int node = blockIdx.x * 4 + wave;
    if (node >= N) return;

    const int d4 = lane * 4;
    const float4 q4 = *reinterpret_cast<const float4*>(Q + (size_t)node * 256 + d4);

    const int beg = row_start[node];
    const int end = row_start[node + 1];

    float4 acc = make_float4(0.f, 0.f, 0.f, 0.f);
    float  ssum = 0.f;

    for (int i = beg; i < end; ++i) {
        const int s = csr_src[i];
        const float4 k4 = *reinterpret_cast<const float4*>(K + (size_t)s * 256 + d4);
        const float4 v4 = *reinterpret_cast<const float4*>(V + (size_t)s * 256 + d4);
        float p = q4.x * k4.x + q4.y * k4.y + q4.z * k4.z + q4.w * k4.w;
        #pragma unroll
        for (int m = 1; m < HL; m <<= 1) p += __shfl_xor(p, m, 64);
        const float a = __expf(p * scale);
        ssum += a;
        acc.x = fmaf(a, v4.x, acc.x);
        acc.y = fmaf(a, v4.y, acc.y);
        acc.z = fmaf(a, v4.z, acc.z);
        acc.w = fmaf(a, v4.w, acc.w);
    }

    float4 o4 = make_float4(0.f, 0.f, 0.f, 0.f);
    if (ssum > 0.f) {
        const float is = 1.f / ssum;
        o4.x = acc.x * is; o4.y = acc.y * is; o4.z = acc.z * is; o4.w = acc.w * is;
    }

    // beta gate: g = sigmoid([out, r, out-r] @ Wb)
    const float4 r4  = *reinterpret_cast<const float4*>(R + (size_t)node * 256 + d4);
    const float4 wb0 = *reinterpret_cast<const float4*>(Wb + d4);
    const float4 wb1 = *reinterpret_cast<const float4*>(Wb + 256 + d4);
    const float4 wb2 = *reinterpret_cast<const float4*>(Wb + 512 + d4);
    float z = o4.x * wb0.x + o4.y * wb0.y + o4.z * wb0.z + o4.w * wb0.w
            + r4.x * wb1.x + r4.y * wb1.y + r4.z * wb1.z + r4.w * wb1.w
            + (o4.x - r4.x) * wb2.x + (o4.y - r4.y) * wb2.y
            + (o4.z - r4.z) * wb2.z + (o4.w - r4.w) * wb2.w;
    #pragma unroll
    for (int m = 1; m < 64; m <<= 1) z += __shfl_xor(z, m, 64);
    const float g = 1.f / (1.f + __expf(-z));

    float4 h4;
    h4.x = g * r4.x + (1.f - g) * o4.x;
    h4.y = g * r4.y + (1.f - g) * o4.y;
    h4.z = g * r4.z + (1.f - g) * o4.z;
    h4.w = g * r4.w + (1.f - g) * o4.w;

    // layernorm over 256 dims
    float s1 = h4.x + h4.y + h4.z + h4.w;
    float s2 = h4.x * h4.x + h4.y * h4.y + h4.z * h4.z + h4.w * h4.w;
    #pragma unroll
    for (int m = 1; m < 64; m <<= 1) {
        s1 += __shfl_xor(s1, m, 64);
        s2 += __shfl_xor(s2, m, 64);
    }
    const float mu  = s1 * (1.f / 256.f);
    const float var = s2 * (1.f / 256.f) - mu * mu;
    const float inv = rsqrtf(var + 1e-5f);

    const float4 ga = *reinterpret_cast<const float4*>(lng + d4);
    const float4 be = *reinterpret_cast<const float4*>(lnb + d4);
    h4.x = (h4.x - mu) * inv * ga.x + be.x;
    h4.y = (h4.y - mu) * inv * ga.y + be.y;
    h4.z = (h4.z - mu) * inv * ga.z + be.z;
    h4.w = (h4.w - mu) * inv * ga.w + be.w;

    if (RELU) {
        h4.x = fmaxf(h4.x, 0.f);
        h4.y = fmaxf(h4.y, 0.f);
        h4.z = fmaxf(h4.z, 0.f);
        h4.w = fmaxf(h4.w, 0.f);
    }

    *reinterpret_cast<float4*>(out + (size_t)node * 256 + d4) = h4;
}

// ------------------------------ mean pool ----------------------------------
__global__ __launch_bounds__(256)
void pool_kernel(const float* __restrict__ h, const int* __restrict__ batch,
                 float* __restrict__ pool, int N)
{
    const int t  = threadIdx.x;          // dim 0..255
    const int n0 = blockIdx.x * 256;
    const int ne = min(n0 + 256, N);
    if (n0 >= N) return;
    float acc = 0.f;
    int cur = batch[n0];
    for (int n = n0; n < ne; ++n) {
        const int g = batch[n];
        if (g != cur) {
            atomicAdd(&pool[(size_t)cur * 256 + t], acc);
            acc = 0.f;
            cur = g;
        }
        acc += h[(size_t)n * 256 + t];
    }
    atomicAdd(&pool[(size_t)cur * 256 + t], acc);
}

__global__ __launch_bounds__(256)
void final_kernel(const float* __restrict__ pool, const int* __restrict__ gcount,
                  float* __restrict__ out)
{
    const int i = blockIdx.x * 256 + threadIdx.x;   // 0..4095
    const int g = i >> 8;
    const float cnt = (float)max(gcount[g], 1);
    out[i] = pool[i] / cnt;
}

// ------------------------------- launcher ----------------------------------
extern "C" void kernel_launch(void* const* d_in, const int* in_sizes, int n_in,
                              void* d_out, int out_size, void* d_ws, size_t ws_size,
                              hipStream_t stream)
{
    const float* x     = (const float*)d_in[0];
    const int*   ei    = (const int*)d_in[1];
    const int*   batch = (const int*)d_in[2];
    const float* Wq0 = (const float*)d_in[3];  const float* bq0 = (const float*)d_in[4];
    const float* Wk0 = (const float*)d_in[5];  const float* bk0 = (const float*)d_in[6];
    const float* Wv0 = (const float*)d_in[7];  const float* bv0 = (const float*)d_in[8];
    const float* Ws0 = (const float*)d_in[9];  const float* bs0 = (const float*)d_in[10];
    const float* Wb0 = (const float*)d_in[11];
    const float* g0  = (const float*)d_in[12]; const float* b0  = (const float*)d_in[13];
    const float* Wq1 = (const float*)d_in[14]; const float* bq1 = (const float*)d_in[15];
    const float* Wk1 = (const float*)d_in[16]; const float* bk1 = (const float*)d_in[17];
    const float* Wv1 = (const float*)d_in[18]; const float* bv1 = (const float*)d_in[19];
    const float* Ws1 = (const float*)d_in[20]; const float* bs1 = (const float*)d_in[21];
    const float* Wb1 = (const float*)d_in[22];
    const float* g1  = (const float*)d_in[23]; const float* b1  = (const float*)d_in[24];

    const int N = in_sizes[0] / 256;
    const int E = in_sizes[1] / 2;
    const int G = 16;

    // workspace layout
    float* fws = (float*)d_ws;
    const size_t NM = (size_t)N * 256;
    float* q    = fws;
    float* k    = q + NM;
    float* v    = k + NM;
    float* r    = v + NM;
    float* h    = r + NM;
    float* pool = h + NM;                       // G*256 floats
    int* deg       = (int*)(pool + (size_t)G * 256);
    int* row_start = deg + N;                   // N+1
    int* cursor    = row_start + N + 1;         // N
    int* gcount    = cursor + N;                // G
    int* csr_src   = gcount + G;                // E

    // zero pool + deg + row_start + cursor + gcount in one contiguous memset
    const size_t zbytes = ((size_t)G * 256 + N + (N + 1) + N + G) * sizeof(int);
    hipMemsetAsync(pool, 0, zbytes, stream);

    const int eb = (E + 255) / 256;
    const int nb = (N + 255) / 256;

    hist_kernel<<<eb, 256, 0, stream>>>(ei, E, deg);
    gcount_kernel<<<nb, 256, 0, stream>>>(batch, N, gcount);
    scan_kernel<<<1, 1024, 0, stream>>>(deg, row_start, N);
    fill_kernel<<<eb, 256, 0, stream>>>(ei, E, row_start, cursor, csr_src);

    const dim3 ggrid((N + 63) / 64, 4, 4);
    const int  agrid = (N + 3) / 4;

    // layer 0
    gemm4_kernel<<<ggrid, 256, 0, stream>>>(x, N,
        Wq0, Wk0, Wv0, Ws0, bq0, bk0, bv0, bs0, q, k, v, r);
    attn_kernel<16, true><<<agrid, 256, 0, stream>>>(
        q, k, v, r, Wb0, g0, b0, row_start, csr_src, h, N, 0.125f);

    // layer 1
    gemm4_kernel<<<ggrid, 256, 0, stream>>>(h, N,
        Wq1, Wk1, Wv1, Ws1, bq1, bk1, bv1, bs1, q, k, v, r);
    attn_kernel<64, false><<<agrid, 256, 0, stream>>>(
        q, k, v, r, Wb1, g1, b1, row_start, csr_src, h, N, 0.0625f);

    // pool
    pool_kernel<<<nb, 256, 0, stream>>>(h, batch, pool, N);
    final_kernel<<<(out_size + 255) / 256, 256, 0, stream>>>(pool, gcount, (float*)d_out);
}

// Round 2
// 362.782 us; speedup vs baseline: 2.3659x; 2.3659x over previous
//
#include <hip/hip_runtime.h>
#include <hip/hip_bf16.h>

// ---------------------------------------------------------------------------
// R1: bf16 MFMA GEMMs (128x128 tile, BK=128, XOR-swizzled LDS), LDS-histogram
// gcount (was 214us of atomic line-bouncing), bf16 q/k/v/r to halve gather
// traffic in attention. Attention math stays f32.
// ---------------------------------------------------------------------------

#define DEVFN static __device__ __forceinline__

typedef __attribute__((ext_vector_type(4))) float f32x4;
typedef __attribute__((ext_vector_type(8))) short bf16x8;

DEVFN float bfu2f(unsigned short u) {
    union { unsigned int i; float f; } t; t.i = ((unsigned)u) << 16; return t.f;
}
DEVFN float4 ldb4(const __hip_bfloat16* p) {
    ushort4 u = *reinterpret_cast<const ushort4*>(p);
    return make_float4(bfu2f(u.x), bfu2f(u.y), bfu2f(u.z), bfu2f(u.w));
}
DEVFN unsigned short f2bu(float f) {
    __hip_bfloat16 b = __float2bfloat16(f);
    return __builtin_bit_cast(unsigned short, b);
}
DEVFN void stb4(__hip_bfloat16* p, float4 v) {
    ushort4 u;
    u.x = f2bu(v.x); u.y = f2bu(v.y); u.z = f2bu(v.z); u.w = f2bu(v.w);
    *reinterpret_cast<ushort4*>(p) = u;
}

// --------------------------- converts ---------------------------------------
__global__ __launch_bounds__(256)
void f2b_kernel(const float* __restrict__ in, __hip_bfloat16* __restrict__ out, int n4)
{
    const int i = blockIdx.x * 256 + threadIdx.x;
    if (i >= n4) return;
    const float4 v = *reinterpret_cast<const float4*>(in + (size_t)i * 4);
    stb4(out + (size_t)i * 4, v);
}

// transpose+convert weights: W[k][c] f32 -> Wt[z][c][k] bf16
__global__ __launch_bounds__(256)
void wconv_kernel(const float* __restrict__ W0, const float* __restrict__ W1,
                  const float* __restrict__ W2, const float* __restrict__ W3,
                  const float* __restrict__ W4, const float* __restrict__ W5,
                  const float* __restrict__ W6, const float* __restrict__ W7,
                  __hip_bfloat16* __restrict__ Wt)
{
    const float* W;
    switch (blockIdx.y) {
        case 0: W = W0; break; case 1: W = W1; break;
        case 2: W = W2; break; case 3: W = W3; break;
        case 4: W = W4; break; case 5: W = W5; break;
        case 6: W = W6; break; default: W = W7; break;
    }
    const int k = blockIdx.x;      // 0..255
    const int c = threadIdx.x;     // 0..255
    Wt[(size_t)blockIdx.y * 65536 + (size_t)c * 256 + k] =
        __float2bfloat16(W[(size_t)k * 256 + c]);
}

// ------------------------- GEMM: O[z] = A @ W[z] + b[z] ---------------------
// A: [M,256] bf16 row-major, Wt: [4][256 cols][256 k] bf16, O: [M,256] bf16
// 128x128 tile, BK=128, 4 waves (2x2), each wave 64x64 via 4x4 16x16x32 frags.
#define SWZ(r, kb) ((r) * 256 + ((kb) ^ (((r) & 7) << 4)))

__global__ __launch_bounds__(256)
void gemm_mfma_kernel(const __hip_bfloat16* __restrict__ A, int M,
                      const __hip_bfloat16* __restrict__ Wt,
                      const float* __restrict__ b0, const float* __restrict__ b1,
                      const float* __restrict__ b2, const float* __restrict__ b3,
                      __hip_bfloat16* __restrict__ O0, __hip_bfloat16* __restrict__ O1,
                      __hip_bfloat16* __restrict__ O2, __hip_bfloat16* __restrict__ O3)
{
    const int z = blockIdx.z;
    const float* bias; __hip_bfloat16* O;
    switch (z) {
        case 0:  bias = b0; O = O0; break;
        case 1:  bias = b1; O = O1; break;
        case 2:  bias = b2; O = O2; break;
        default: bias = b3; O = O3; break;
    }
    const __hip_bfloat16* Wz = Wt + (size_t)z * 65536;

    __shared__ char As[128 * 256];   // 128 rows x 128 k x 2B, swizzled
    __shared__ char Bs[128 * 256];   // 128 cols x 128 k x 2B, swizzled

    const int tid  = threadIdx.x;
    const int row0 = blockIdx.x * 128;
    const int col0 = blockIdx.y * 128;
    const int wid  = tid >> 6, lane = tid & 63;
    const int wr   = wid >> 1, wc = wid & 1;
    const int lrow = lane & 15, kg = lane >> 4;

    const int chunk = tid & 15;    // 16B chunk within the 256B k-row
    const int rsub  = tid >> 4;    // 0..15

    f32x4 acc[4][4] = {};

    for (int k0 = 0; k0 < 256; k0 += 128) {
        #pragma unroll
        for (int p = 0; p < 8; ++p) {
            const int r  = p * 16 + rsub;
            const int gr = row0 + r;
            ulonglong2 av = {0ull, 0ull};
            if (gr < M)
                av = *reinterpret_cast<const ulonglong2*>(A + (size_t)gr * 256 + k0 + chunk * 8);
            *reinterpret_cast<ulonglong2*>(As + SWZ(r, chunk * 16)) = av;

            const ulonglong2 bv = *reinterpret_cast<const ulonglong2*>(
                Wz + (size_t)(col0 + r) * 256 + k0 + chunk * 8);
            *reinterpret_cast<ulonglong2*>(Bs + SWZ(r, chunk * 16)) = bv;
        }
        __syncthreads();

        #pragma unroll
        for (int kk = 0; kk < 128; kk += 32) {
            const int kbyte = kk * 2 + kg * 16;
            bf16x8 af[4], bfr[4];
            #pragma unroll
            for (int m = 0; m < 4; ++m) {
                const int r = wr * 64 + m * 16 + lrow;
                af[m] = *reinterpret_cast<const bf16x8*>(As + SWZ(r, kbyte));
            }
            #pragma unroll
            for (int n = 0; n < 4; ++n) {
                const int c = wc * 64 + n * 16 + lrow;
                bfr[n] = *reinterpret_cast<const bf16x8*>(Bs + SWZ(c, kbyte));
            }
            #pragma unroll
            for (int m = 0; m < 4; ++m)
                #pragma unroll
                for (int n = 0; n < 4; ++n)
                    acc[m][n] = __builtin_amdgcn_mfma_f32_16x16x32_bf16(
                        af[m], bfr[n], acc[m][n], 0, 0, 0);
        }
        __syncthreads();
    }

    // epilogue: C/D layout col=lane&15, row=(lane>>4)*4+reg
    #pragma unroll
    for (int m = 0; m < 4; ++m) {
        #pragma unroll
        for (int j = 0; j < 4; ++j) {
            const int grow = row0 + wr * 64 + m * 16 + kg * 4 + j;
            if (grow >= M) continue;
            #pragma unroll
            for (int n = 0; n < 4; ++n) {
                const int gcol = col0 + wc * 64 + n * 16 + lrow;
                const float v = acc[m][n][j] + bias[gcol];
                O[(size_t)grow * 256 + gcol] = __float2bfloat16(v);
            }
        }
    }
}

// ------------------------------ CSR build ----------------------------------
__global__ __launch_bounds__(256)
void hist_kernel(const int* __restrict__ ei, int E, int* __restrict__ deg)
{
    const int e = blockIdx.x * 256 + threadIdx.x;
    if (e < E) atomicAdd(&deg[ei[E + e]], 1);
}

// LDS histogram for the 16 graph-ids (batch is sorted; global atomics on one
// cache line were 214us in R0)
__global__ __launch_bounds__(256)
void gcount_kernel(const int* __restrict__ batch, int N, int* __restrict__ gcount)
{
    __shared__ int h[16];
    if (threadIdx.x < 16) h[threadIdx.x] = 0;
    __syncthreads();
    const int n = blockIdx.x * 256 + threadIdx.x;
    if (n < N) atomicAdd(&h[batch[n]], 1);
    __syncthreads();
    if (threadIdx.x < 16 && h[threadIdx.x] != 0)
        atomicAdd(&gcount[threadIdx.x], h[threadIdx.x]);
}

__global__ __launch_bounds__(1024)
void scan_kernel(const int* __restrict__ deg, int* __restrict__ row_start, int n)
{
    __shared__ int sh[1024];
    const int tid = threadIdx.x;
    if (tid == 0) row_start[0] = 0;
    int offset = 0;
    for (int base = 0; base < n; base += 1024) {
        const int idx = base + tid;
        sh[tid] = (idx < n) ? deg[idx] : 0;
        __syncthreads();
        #pragma unroll
        for (int d = 1; d < 1024; d <<= 1) {
            const int t = (tid >= d) ? sh[tid - d] : 0;
            __syncthreads();
            sh[tid] += t;
            __syncthreads();
        }
        if (idx < n) row_start[idx + 1] = offset + sh[tid];
        offset += sh[1023];
        __syncthreads();
    }
}

__global__ __launch_bounds__(256)
void fill_kernel(const int* __restrict__ ei, int E,
                 const int* __restrict__ row_start,
                 int* __restrict__ cursor, int* __restrict__ csr_src)
{
    const int e = blockIdx.x * 256 + threadIdx.x;
    if (e >= E) return;
    const int s = ei[e];
    const int d = ei[E + e];
    const int pos = atomicAdd(&cursor[d], 1);
    csr_src[row_start[d] + pos] = s;
}

// --------------------- fused attention + gate + layernorm ------------------
template <int HL, bool RELU, bool OUTB>
__global__ __launch_bounds__(256)
void attn_kernel(const __hip_bfloat16* __restrict__ Q, const __hip_bfloat16* __restrict__ K,
                 const __hip_bfloat16* __restrict__ V, const __hip_bfloat16* __restrict__ R,
                 const float* __restrict__ Wb, const float* __restrict__ lng,
                 const float* __restrict__ lnb,
                 const int* __restrict__ row_start, const int* __restrict__ csr_src,
                 __hip_bfloat16* __restrict__ outb, float* __restrict__ outf,
                 int N, float scale)
{
    const int wave = threadIdx.x >> 6;
    const int lane = threadIdx.x & 63;
    const int node = blockIdx.x * 4 + wave;
    if (node >= N) return;

    const int d4 = lane * 4;
    const float4 q4 = ldb4(Q + (size_t)node * 256 + d4);

    const int beg = row_start[node];
    const int end = row_start[node + 1];

    float4 acc = make_float4(0.f, 0.f, 0.f, 0.f);
    float  ssum = 0.f;

    for (int i = beg; i < end; ++i) {
        const int s = csr_src[i];
        const float4 k4 = ldb4(K + (size_t)s * 256 + d4);
        const float4 v4 = ldb4(V + (size_t)s * 256 + d4);
        float p = q4.x * k4.x + q4.y * k4.y + q4.z * k4.z + q4.w * k4.w;
        #pragma unroll
        for (int m = 1; m < HL; m <<= 1) p += __shfl_xor(p, m, 64);
        const float a = __expf(p * scale);
        ssum += a;
        acc.x = fmaf(a, v4.x, acc.x);
        acc.y = fmaf(a, v4.y, acc.y);
        acc.z = fmaf(a, v4.z, acc.z);
        acc.w = fmaf(a, v4.w, acc.w);
    }

    float4 o4 = make_float4(0.f, 0.f, 0.f, 0.f);
    if (ssum > 0.f) {
        const float is = 1.f / ssum;
        o4.x = acc.x * is; o4.y = acc.y * is; o4.z = acc.z * is; o4.w = acc.w * is;
    }

    const float4 r4  = ldb4(R + (size_t)node * 256 + d4);
    const float4 wb0 = *reinterpret_cast<const float4*>(Wb + d4);
    const float4 wb1 = *reinterpret_cast<const float4*>(Wb + 256 + d4);
    const float4 wb2 = *reinterpret_cast<const float4*>(Wb + 512 + d4);
    float z = o4.x * wb0.x + o4.y * wb0.y + o4.z * wb0.z + o4.w * wb0.w
            + r4.x * wb1.x + r4.y * wb1.y + r4.z * wb1.z + r4.w * wb1.w
            + (o4.x - r4.x) * wb2.x + (o4.y - r4.y) * wb2.y
            + (o4.z - r4.z) * wb2.z + (o4.w - r4.w) * wb2.w;
    #pragma unroll
    for (int m = 1; m < 64; m <<= 1) z += __shfl_xor(z, m, 64);
    const float g = 1.f / (1.f + __expf(-z));

    float4 h4;
    h4.x = g * r4.x + (1.f - g) * o4.x;
    h4.y = g * r4.y + (1.f - g) * o4.y;
    h4.z = g * r4.z + (1.f - g) * o4.z;
    h4.w = g * r4.w + (1.f - g) * o4.w;

    float s1 = h4.x + h4.y + h4.z + h4.w;
    float s2 = h4.x * h4.x + h4.y * h4.y + h4.z * h4.z + h4.w * h4.w;
    #pragma unroll
    for (int m = 1; m < 64; m <<= 1) {
        s1 += __shfl_xor(s1, m, 64);
        s2 += __shfl_xor(s2, m, 64);
    }
    const float mu  = s1 * (1.f / 256.f);
    const float var = s2 * (1.f / 256.f) - mu * mu;
    const float inv = rsqrtf(var + 1e-5f);

    const float4 ga = *reinterpret_cast<const float4*>(lng + d4);
    const float4 be = *reinterpret_cast<const float4*>(lnb + d4);
    h4.x = (h4.x - mu) * inv * ga.x + be.x;
    h4.y = (h4.y - mu) * inv * ga.y + be.y;
    h4.z = (h4.z - mu) * inv * ga.z + be.z;
    h4.w = (h4.w - mu) * inv * ga.w + be.w;

    if (RELU) {
        h4.x = fmaxf(h4.x, 0.f);
        h4.y = fmaxf(h4.y, 0.f);
        h4.z = fmaxf(h4.z, 0.f);
        h4.w = fmaxf(h4.w, 0.f);
    }

    if (OUTB) stb4(outb + (size_t)node * 256 + d4, h4);
    else      *reinterpret_cast<float4*>(outf + (size_t)node * 256 + d4) = h4;
}

// ------------------------------ mean pool ----------------------------------
__global__ __launch_bounds__(256)
void pool_kernel(const float* __restrict__ h, const int* __restrict__ batch,
                 float* __restrict__ pool, int N)
{
    const int t  = threadIdx.x;
    const int n0 = blockIdx.x * 256;
    const int ne = min(n0 + 256, N);
    if (n0 >= N) return;
    float acc = 0.f;
    int cur = batch[n0];
    for (int n = n0; n < ne; ++n) {
        const int g = batch[n];
        if (g != cur) {
            atomicAdd(&pool[(size_t)cur * 256 + t], acc);
            acc = 0.f;
            cur = g;
        }
        acc += h[(size_t)n * 256 + t];
    }
    atomicAdd(&pool[(size_t)cur * 256 + t], acc);
}

__global__ __launch_bounds__(256)
void final_kernel(const float* __restrict__ pool, const int* __restrict__ gcount,
                  float* __restrict__ out)
{
    const int i = blockIdx.x * 256 + threadIdx.x;
    const int g = i >> 8;
    const float cnt = (float)max(gcount[g], 1);
    out[i] = pool[i] / cnt;
}

// ------------------------------- launcher ----------------------------------
extern "C" void kernel_launch(void* const* d_in, const int* in_sizes, int n_in,
                              void* d_out, int out_size, void* d_ws, size_t ws_size,
                              hipStream_t stream)
{
    const float* x     = (const float*)d_in[0];
    const int*   ei    = (const int*)d_in[1];
    const int*   batch = (const int*)d_in[2];
    const float* Wq0 = (const float*)d_in[3];  const float* bq0 = (const float*)d_in[4];
    const float* Wk0 = (const float*)d_in[5];  const float* bk0 = (const float*)d_in[6];
    const float* Wv0 = (const float*)d_in[7];  const float* bv0 = (const float*)d_in[8];
    const float* Ws0 = (const float*)d_in[9];  const float* bs0 = (const float*)d_in[10];
    const float* Wb0 = (const float*)d_in[11];
    const float* g0  = (const float*)d_in[12]; const float* b0  = (const float*)d_in[13];
    const float* Wq1 = (const float*)d_in[14]; const float* bq1 = (const float*)d_in[15];
    const float* Wk1 = (const float*)d_in[16]; const float* bk1 = (const float*)d_in[17];
    const float* Wv1 = (const float*)d_in[18]; const float* bv1 = (const float*)d_in[19];
    const float* Ws1 = (const float*)d_in[20]; const float* bs1 = (const float*)d_in[21];
    const float* Wb1 = (const float*)d_in[22];
    const float* g1  = (const float*)d_in[23]; const float* b1  = (const float*)d_in[24];

    const int N = in_sizes[0] / 256;
    const int E = in_sizes[1] / 2;
    const int G = 16;
    const size_t NM = (size_t)N * 256;

    // workspace layout (bf16 first, then f32, then ints)
    __hip_bfloat16* bws = (__hip_bfloat16*)d_ws;
    __hip_bfloat16* xb  = bws;
    __hip_bfloat16* qb  = xb  + NM;
    __hip_bfloat16* kb  = qb  + NM;
    __hip_bfloat16* vb  = kb  + NM;
    __hip_bfloat16* rb  = vb  + NM;
    __hip_bfloat16* h0b = rb  + NM;
    __hip_bfloat16* wt  = h0b + NM;               // 8 * 65536 bf16
    float* h1f  = (float*)(wt + 8 * 65536);
    float* pool = h1f + NM;                       // G*256
    int* deg       = (int*)(pool + (size_t)G * 256);
    int* row_start = deg + N;
    int* cursor    = row_start + N + 1;
    int* gcount    = cursor + N;
    int* csr_src   = gcount + G;

    const size_t zbytes = ((size_t)G * 256 + N + (N + 1) + N + G) * sizeof(int);
    hipMemsetAsync(pool, 0, zbytes, stream);

    const int eb = (E + 255) / 256;
    const int nb = (N + 255) / 256;

    // converts
    f2b_kernel<<<(int)((NM / 4 + 255) / 256), 256, 0, stream>>>(x, xb, (int)(NM / 4));
    wconv_kernel<<<dim3(256, 8), 256, 0, stream>>>(Wq0, Wk0, Wv0, Ws0,
                                                   Wq1, Wk1, Wv1, Ws1, wt);

    // CSR
    hist_kernel<<<eb, 256, 0, stream>>>(ei, E, deg);
    gcount_kernel<<<nb, 256, 0, stream>>>(batch, N, gcount);
    scan_kernel<<<1, 1024, 0, stream>>>(deg, row_start, N);
    fill_kernel<<<eb, 256, 0, stream>>>(ei, E, row_start, cursor, csr_src);

    const dim3 ggrid((N + 127) / 128, 2, 4);
    const int  agrid = (N + 3) / 4;

    // layer 0
    gemm_mfma_kernel<<<ggrid, 256, 0, stream>>>(xb, N, wt,
        bq0, bk0, bv0, bs0, qb, kb, vb, rb);
    attn_kernel<16, true, true><<<agrid, 256, 0, stream>>>(
        qb, kb, vb, rb, Wb0, g0, b0, row_start, csr_src, h0b, nullptr, N, 0.125f);

    // layer 1
    gemm_mfma_kernel<<<ggrid, 256, 0, stream>>>(h0b, N, wt + 4 * 65536,
        bq1, bk1, bv1, bs1, qb, kb, vb, rb);
    attn_kernel<64, false, false><<<agrid, 256, 0, stream>>>(
        qb, kb, vb, rb, Wb1, g1, b1, row_start, csr_src, nullptr, h1f, N, 0.0625f);

    // pool
    pool_kernel<<<nb, 256, 0, stream>>>(h1f, batch, pool, N);
    final_kernel<<<(out_size + 255) / 256, 256, 0, stream>>>(pool, gcount, (float*)d_out);
}

// Round 3
// 284.530 us; speedup vs baseline: 3.0165x; 1.2750x over previous
//
#include <hip/hip_runtime.h>
#include <hip/hip_bf16.h>

// ---------------------------------------------------------------------------
// R2: fix the two latency-bound serial kernels found in R1 profile:
//   - pool: 71us @ 1.8% HBM, 79 blocks serial-row loop -> two-stage segmented
//     reduction (16 graphs x 16 slices, whole-row coalesced waves, no atomics)
//   - scan: ~600 barrier rounds -> shfl wave-scan + cross-wave scan (60 barriers)
// GEMMs (bf16 MFMA 128x128) and fused attention unchanged from R1.
// ---------------------------------------------------------------------------

#define DEVFN static __device__ __forceinline__

typedef __attribute__((ext_vector_type(4))) float f32x4;
typedef __attribute__((ext_vector_type(8))) short bf16x8;

DEVFN float bfu2f(unsigned short u) {
    union { unsigned int i; float f; } t; t.i = ((unsigned)u) << 16; return t.f;
}
DEVFN float4 ldb4(const __hip_bfloat16* p) {
    ushort4 u = *reinterpret_cast<const ushort4*>(p);
    return make_float4(bfu2f(u.x), bfu2f(u.y), bfu2f(u.z), bfu2f(u.w));
}
DEVFN unsigned short f2bu(float f) {
    __hip_bfloat16 b = __float2bfloat16(f);
    return __builtin_bit_cast(unsigned short, b);
}
DEVFN void stb4(__hip_bfloat16* p, float4 v) {
    ushort4 u;
    u.x = f2bu(v.x); u.y = f2bu(v.y); u.z = f2bu(v.z); u.w = f2bu(v.w);
    *reinterpret_cast<ushort4*>(p) = u;
}

// --------------------------- converts ---------------------------------------
__global__ __launch_bounds__(256)
void f2b_kernel(const float* __restrict__ in, __hip_bfloat16* __restrict__ out, int n4)
{
    const int i = blockIdx.x * 256 + threadIdx.x;
    if (i >= n4) return;
    const float4 v = *reinterpret_cast<const float4*>(in + (size_t)i * 4);
    stb4(out + (size_t)i * 4, v);
}

// transpose+convert weights: W[k][c] f32 -> Wt[z][c][k] bf16
__global__ __launch_bounds__(256)
void wconv_kernel(const float* __restrict__ W0, const float* __restrict__ W1,
                  const float* __restrict__ W2, const float* __restrict__ W3,
                  const float* __restrict__ W4, const float* __restrict__ W5,
                  const float* __restrict__ W6, const float* __restrict__ W7,
                  __hip_bfloat16* __restrict__ Wt)
{
    const float* W;
    switch (blockIdx.y) {
        case 0: W = W0; break; case 1: W = W1; break;
        case 2: W = W2; break; case 3: W = W3; break;
        case 4: W = W4; break; case 5: W = W5; break;
        case 6: W = W6; break; default: W = W7; break;
    }
    const int k = blockIdx.x;      // 0..255
    const int c = threadIdx.x;     // 0..255
    Wt[(size_t)blockIdx.y * 65536 + (size_t)c * 256 + k] =
        __float2bfloat16(W[(size_t)k * 256 + c]);
}

// ------------------------- GEMM: O[z] = A @ W[z] + b[z] ---------------------
#define SWZ(r, kb) ((r) * 256 + ((kb) ^ (((r) & 7) << 4)))

__global__ __launch_bounds__(256)
void gemm_mfma_kernel(const __hip_bfloat16* __restrict__ A, int M,
                      const __hip_bfloat16* __restrict__ Wt,
                      const float* __restrict__ b0, const float* __restrict__ b1,
                      const float* __restrict__ b2, const float* __restrict__ b3,
                      __hip_bfloat16* __restrict__ O0, __hip_bfloat16* __restrict__ O1,
                      __hip_bfloat16* __restrict__ O2, __hip_bfloat16* __restrict__ O3)
{
    const int z = blockIdx.z;
    const float* bias; __hip_bfloat16* O;
    switch (z) {
        case 0:  bias = b0; O = O0; break;
        case 1:  bias = b1; O = O1; break;
        case 2:  bias = b2; O = O2; break;
        default: bias = b3; O = O3; break;
    }
    const __hip_bfloat16* Wz = Wt + (size_t)z * 65536;

    __shared__ char As[128 * 256];
    __shared__ char Bs[128 * 256];

    const int tid  = threadIdx.x;
    const int row0 = blockIdx.x * 128;
    const int col0 = blockIdx.y * 128;
    const int wid  = tid >> 6, lane = tid & 63;
    const int wr   = wid >> 1, wc = wid & 1;
    const int lrow = lane & 15, kg = lane >> 4;

    const int chunk = tid & 15;
    const int rsub  = tid >> 4;

    f32x4 acc[4][4] = {};

    for (int k0 = 0; k0 < 256; k0 += 128) {
        #pragma unroll
        for (int p = 0; p < 8; ++p) {
            const int r  = p * 16 + rsub;
            const int gr = row0 + r;
            ulonglong2 av = {0ull, 0ull};
            if (gr < M)
                av = *reinterpret_cast<const ulonglong2*>(A + (size_t)gr * 256 + k0 + chunk * 8);
            *reinterpret_cast<ulonglong2*>(As + SWZ(r, chunk * 16)) = av;

            const ulonglong2 bv = *reinterpret_cast<const ulonglong2*>(
                Wz + (size_t)(col0 + r) * 256 + k0 + chunk * 8);
            *reinterpret_cast<ulonglong2*>(Bs + SWZ(r, chunk * 16)) = bv;
        }
        __syncthreads();

        #pragma unroll
        for (int kk = 0; kk < 128; kk += 32) {
            const int kbyte = kk * 2 + kg * 16;
            bf16x8 af[4], bfr[4];
            #pragma unroll
            for (int m = 0; m < 4; ++m) {
                const int r = wr * 64 + m * 16 + lrow;
                af[m] = *reinterpret_cast<const bf16x8*>(As + SWZ(r, kbyte));
            }
            #pragma unroll
            for (int n = 0; n < 4; ++n) {
                const int c = wc * 64 + n * 16 + lrow;
                bfr[n] = *reinterpret_cast<const bf16x8*>(Bs + SWZ(c, kbyte));
            }
            #pragma unroll
            for (int m = 0; m < 4; ++m)
                #pragma unroll
                for (int n = 0; n < 4; ++n)
                    acc[m][n] = __builtin_amdgcn_mfma_f32_16x16x32_bf16(
                        af[m], bfr[n], acc[m][n], 0, 0, 0);
        }
        __syncthreads();
    }

    #pragma unroll
    for (int m = 0; m < 4; ++m) {
        #pragma unroll
        for (int j = 0; j < 4; ++j) {
            const int grow = row0 + wr * 64 + m * 16 + kg * 4 + j;
            if (grow >= M) continue;
            #pragma unroll
            for (int n = 0; n < 4; ++n) {
                const int gcol = col0 + wc * 64 + n * 16 + lrow;
                const float v = acc[m][n][j] + bias[gcol];
                O[(size_t)grow * 256 + gcol] = __float2bfloat16(v);
            }
        }
    }
}

// ------------------------------ CSR build ----------------------------------
__global__ __launch_bounds__(256)
void hist_kernel(const int* __restrict__ ei, int E, int* __restrict__ deg)
{
    const int e = blockIdx.x * 256 + threadIdx.x;
    if (e < E) atomicAdd(&deg[ei[E + e]], 1);
}

__global__ __launch_bounds__(256)
void gcount_kernel(const int* __restrict__ batch, int N, int* __restrict__ gcount)
{
    __shared__ int h[16];
    if (threadIdx.x < 16) h[threadIdx.x] = 0;
    __syncthreads();
    const int n = blockIdx.x * 256 + threadIdx.x;
    if (n < N) atomicAdd(&h[batch[n]], 1);
    __syncthreads();
    if (threadIdx.x < 16 && h[threadIdx.x] != 0)
        atomicAdd(&gcount[threadIdx.x], h[threadIdx.x]);
}

__global__ __launch_bounds__(64)
void gstart_kernel(const int* __restrict__ gcount, int* __restrict__ gstart)
{
    if (threadIdx.x == 0) {
        int o = 0;
        for (int g = 0; g < 16; ++g) { gstart[g] = o; o += gcount[g]; }
        gstart[16] = o;
    }
}

// shfl-based scan: wave inclusive scan, cross-wave scan, 3 barriers per chunk
__global__ __launch_bounds__(1024)
void scan_kernel(const int* __restrict__ deg, int* __restrict__ row_start, int n)
{
    __shared__ int wsum[16];
    __shared__ int wincl[16];
    const int tid  = threadIdx.x;
    const int w    = tid >> 6;
    const int lane = tid & 63;
    if (tid == 0) row_start[0] = 0;
    int offset = 0;
    for (int base = 0; base < n; base += 1024) {
        const int idx = base + tid;
        int s = (idx < n) ? deg[idx] : 0;
        #pragma unroll
        for (int d = 1; d < 64; d <<= 1) {
            const int t = __shfl_up(s, d, 64);
            if (lane >= d) s += t;
        }
        if (lane == 63) wsum[w] = s;
        __syncthreads();
        if (tid < 16) {
            int si = wsum[tid];
            #pragma unroll
            for (int d = 1; d < 16; d <<= 1) {
                const int u = __shfl_up(si, d, 64);
                if (tid >= d) si += u;
            }
            wincl[tid] = si;
        }
        __syncthreads();
        const int woff = (w > 0) ? wincl[w - 1] : 0;
        if (idx < n) row_start[idx + 1] = offset + woff + s;
        offset += wincl[15];
        __syncthreads();
    }
}

__global__ __launch_bounds__(256)
void fill_kernel(const int* __restrict__ ei, int E,
                 const int* __restrict__ row_start,
                 int* __restrict__ cursor, int* __restrict__ csr_src)
{
    const int e = blockIdx.x * 256 + threadIdx.x;
    if (e >= E) return;
    const int s = ei[e];
    const int d = ei[E + e];
    const int pos = atomicAdd(&cursor[d], 1);
    csr_src[row_start[d] + pos] = s;
}

// --------------------- fused attention + gate + layernorm ------------------
template <int HL, bool RELU, bool OUTB>
__global__ __launch_bounds__(256)
void attn_kernel(const __hip_bfloat16* __restrict__ Q, const __hip_bfloat16* __restrict__ K,
                 const __hip_bfloat16* __restrict__ V, const __hip_bfloat16* __restrict__ R,
                 const float* __restrict__ Wb, const float* __restrict__ lng,
                 const float* __restrict__ lnb,
                 const int* __restrict__ row_start, const int* __restrict__ csr_src,
                 __hip_bfloat16* __restrict__ outb, float* __restrict__ outf,
                 int N, float scale)
{
    const int wave = threadIdx.x >> 6;
    const int lane = threadIdx.x & 63;
    const int node = blockIdx.x * 4 + wave;
    if (node >= N) return;

    const int d4 = lane * 4;
    const float4 q4 = ldb4(Q + (size_t)node * 256 + d4);

    const int beg = row_start[node];
    const int end = row_start[node + 1];

    float4 acc = make_float4(0.f, 0.f, 0.f, 0.f);
    float  ssum = 0.f;

    for (int i = beg; i < end; ++i) {
        const int s = csr_src[i];
        const float4 k4 = ldb4(K + (size_t)s * 256 + d4);
        const float4 v4 = ldb4(V + (size_t)s * 256 + d4);
        float p = q4.x * k4.x + q4.y * k4.y + q4.z * k4.z + q4.w * k4.w;
        #pragma unroll
        for (int m = 1; m < HL; m <<= 1) p += __shfl_xor(p, m, 64);
        const float a = __expf(p * scale);
        ssum += a;
        acc.x = fmaf(a, v4.x, acc.x);
        acc.y = fmaf(a, v4.y, acc.y);
        acc.z = fmaf(a, v4.z, acc.z);
        acc.w = fmaf(a, v4.w, acc.w);
    }

    float4 o4 = make_float4(0.f, 0.f, 0.f, 0.f);
    if (ssum > 0.f) {
        const float is = 1.f / ssum;
        o4.x = acc.x * is; o4.y = acc.y * is; o4.z = acc.z * is; o4.w = acc.w * is;
    }

    const float4 r4  = ldb4(R + (size_t)node * 256 + d4);
    const float4 wb0 = *reinterpret_cast<const float4*>(Wb + d4);
    const float4 wb1 = *reinterpret_cast<const float4*>(Wb + 256 + d4);
    const float4 wb2 = *reinterpret_cast<const float4*>(Wb + 512 + d4);
    float z = o4.x * wb0.x + o4.y * wb0.y + o4.z * wb0.z + o4.w * wb0.w
            + r4.x * wb1.x + r4.y * wb1.y + r4.z * wb1.z + r4.w * wb1.w
            + (o4.x - r4.x) * wb2.x + (o4.y - r4.y) * wb2.y
            + (o4.z - r4.z) * wb2.z + (o4.w - r4.w) * wb2.w;
    #pragma unroll
    for (int m = 1; m < 64; m <<= 1) z += __shfl_xor(z, m, 64);
    const float g = 1.f / (1.f + __expf(-z));

    float4 h4;
    h4.x = g * r4.x + (1.f - g) * o4.x;
    h4.y = g * r4.y + (1.f - g) * o4.y;
    h4.z = g * r4.z + (1.f - g) * o4.z;
    h4.w = g * r4.w + (1.f - g) * o4.w;

    float s1 = h4.x + h4.y + h4.z + h4.w;
    float s2 = h4.x * h4.x + h4.y * h4.y + h4.z * h4.z + h4.w * h4.w;
    #pragma unroll
    for (int m = 1; m < 64; m <<= 1) {
        s1 += __shfl_xor(s1, m, 64);
        s2 += __shfl_xor(s2, m, 64);
    }
    const float mu  = s1 * (1.f / 256.f);
    const float var = s2 * (1.f / 256.f) - mu * mu;
    const float inv = rsqrtf(var + 1e-5f);

    const float4 ga = *reinterpret_cast<const float4*>(lng + d4);
    const float4 be = *reinterpret_cast<const float4*>(lnb + d4);
    h4.x = (h4.x - mu) * inv * ga.x + be.x;
    h4.y = (h4.y - mu) * inv * ga.y + be.y;
    h4.z = (h4.z - mu) * inv * ga.z + be.z;
    h4.w = (h4.w - mu) * inv * ga.w + be.w;

    if (RELU) {
        h4.x = fmaxf(h4.x, 0.f);
        h4.y = fmaxf(h4.y, 0.f);
        h4.z = fmaxf(h4.z, 0.f);
        h4.w = fmaxf(h4.w, 0.f);
    }

    if (OUTB) stb4(outb + (size_t)node * 256 + d4, h4);
    else      *reinterpret_cast<float4*>(outf + (size_t)node * 256 + d4) = h4;
}

// ------------------------------ mean pool (two-stage) ----------------------
// Stage A: block (slice s, graph g); wave lanes = 64 quads -> whole 1KB rows
// coalesced; LDS-reduce the 4 row-groups; write partial[g][s][256]. No atomics.
__global__ __launch_bounds__(256)
void pool_partial_kernel(const float* __restrict__ h, const int* __restrict__ gstart,
                         float* __restrict__ partial)
{
    const int s    = blockIdx.x;        // 0..15 slice
    const int g    = blockIdx.y;        // 0..15 graph
    const int tid  = threadIdx.x;
    const int quad = tid & 63;
    const int sub  = tid >> 6;

    const int beg = gstart[g];
    const int cnt = gstart[g + 1] - beg;

    f32x4 acc = {0.f, 0.f, 0.f, 0.f};
    for (int i = s * 4 + sub; i < cnt; i += 64) {
        const f32x4 v = *reinterpret_cast<const f32x4*>(
            h + (size_t)(beg + i) * 256 + quad * 4);
        acc += v;
    }

    __shared__ f32x4 sh[4][64];
    sh[sub][quad] = acc;
    __syncthreads();
    if (sub == 0) {
        const f32x4 r = sh[0][quad] + sh[1][quad] + sh[2][quad] + sh[3][quad];
        *reinterpret_cast<f32x4*>(partial + ((size_t)(g * 16 + s) * 64 + quad) * 4) = r;
    }
}

__global__ __launch_bounds__(256)
void pool_final_kernel(const float* __restrict__ partial, const int* __restrict__ gcount,
                       float* __restrict__ out)
{
    const int g = blockIdx.x;           // 0..15
    const int d = threadIdx.x;          // 0..255
    float sum = 0.f;
    #pragma unroll
    for (int s = 0; s < 16; ++s)
        sum += partial[(size_t)(g * 16 + s) * 256 + d];
    out[(size_t)g * 256 + d] = sum / (float)max(gcount[g], 1);
}

// ------------------------------- launcher ----------------------------------
extern "C" void kernel_launch(void* const* d_in, const int* in_sizes, int n_in,
                              void* d_out, int out_size, void* d_ws, size_t ws_size,
                              hipStream_t stream)
{
    const float* x     = (const float*)d_in[0];
    const int*   ei    = (const int*)d_in[1];
    const int*   batch = (const int*)d_in[2];
    const float* Wq0 = (const float*)d_in[3];  const float* bq0 = (const float*)d_in[4];
    const float* Wk0 = (const float*)d_in[5];  const float* bk0 = (const float*)d_in[6];
    const float* Wv0 = (const float*)d_in[7];  const float* bv0 = (const float*)d_in[8];
    const float* Ws0 = (const float*)d_in[9];  const float* bs0 = (const float*)d_in[10];
    const float* Wb0 = (const float*)d_in[11];
    const float* g0  = (const float*)d_in[12]; const float* b0  = (const float*)d_in[13];
    const float* Wq1 = (const float*)d_in[14]; const float* bq1 = (const float*)d_in[15];
    const float* Wk1 = (const float*)d_in[16]; const float* bk1 = (const float*)d_in[17];
    const float* Wv1 = (const float*)d_in[18]; const float* bv1 = (const float*)d_in[19];
    const float* Ws1 = (const float*)d_in[20]; const float* bs1 = (const float*)d_in[21];
    const float* Wb1 = (const float*)d_in[22];
    const float* g1  = (const float*)d_in[23]; const float* b1  = (const float*)d_in[24];

    const int N = in_sizes[0] / 256;
    const int E = in_sizes[1] / 2;
    const int G = 16;
    const size_t NM = (size_t)N * 256;

    __hip_bfloat16* bws = (__hip_bfloat16*)d_ws;
    __hip_bfloat16* xb  = bws;
    __hip_bfloat16* qb  = xb  + NM;
    __hip_bfloat16* kb  = qb  + NM;
    __hip_bfloat16* vb  = kb  + NM;
    __hip_bfloat16* rb  = vb  + NM;
    __hip_bfloat16* h0b = rb  + NM;
    __hip_bfloat16* wt  = h0b + NM;               // 8 * 65536 bf16
    float* h1f     = (float*)(wt + 8 * 65536);
    float* partial = h1f + NM;                    // 16*16*256 f32
    int* deg       = (int*)(partial + 16 * 16 * 256);
    int* row_start = deg + N;
    int* cursor    = row_start + N + 1;
    int* gcount    = cursor + N;
    int* gstart    = gcount + G;                  // 17
    int* csr_src   = gstart + 17;

    // zero deg + row_start + cursor + gcount + gstart (contiguous)
    const size_t zbytes = ((size_t)N + (N + 1) + N + G + 17) * sizeof(int);
    hipMemsetAsync(deg, 0, zbytes, stream);

    const int eb = (E + 255) / 256;
    const int nb = (N + 255) / 256;

    f2b_kernel<<<(int)((NM / 4 + 255) / 256), 256, 0, stream>>>(x, xb, (int)(NM / 4));
    wconv_kernel<<<dim3(256, 8), 256, 0, stream>>>(Wq0, Wk0, Wv0, Ws0,
                                                   Wq1, Wk1, Wv1, Ws1, wt);

    hist_kernel<<<eb, 256, 0, stream>>>(ei, E, deg);
    gcount_kernel<<<nb, 256, 0, stream>>>(batch, N, gcount);
    gstart_kernel<<<1, 64, 0, stream>>>(gcount, gstart);
    scan_kernel<<<1, 1024, 0, stream>>>(deg, row_start, N);
    fill_kernel<<<eb, 256, 0, stream>>>(ei, E, row_start, cursor, csr_src);

    const dim3 ggrid((N + 127) / 128, 2, 4);
    const int  agrid = (N + 3) / 4;

    gemm_mfma_kernel<<<ggrid, 256, 0, stream>>>(xb, N, wt,
        bq0, bk0, bv0, bs0, qb, kb, vb, rb);
    attn_kernel<16, true, true><<<agrid, 256, 0, stream>>>(
        qb, kb, vb, rb, Wb0, g0, b0, row_start, csr_src, h0b, nullptr, N, 0.125f);

    gemm_mfma_kernel<<<ggrid, 256, 0, stream>>>(h0b, N, wt + 4 * 65536,
        bq1, bk1, bv1, bs1, qb, kb, vb, rb);
    attn_kernel<64, false, false><<<agrid, 256, 0, stream>>>(
        qb, kb, vb, rb, Wb1, g1, b1, row_start, csr_src, nullptr, h1f, N, 0.0625f);

    pool_partial_kernel<<<dim3(16, 16), 256, 0, stream>>>(h1f, gstart, partial);
    pool_final_kernel<<<16, 256, 0, stream>>>(partial, gcount, (float*)d_out);
}

// Round 4
// 261.092 us; speedup vs baseline: 3.2873x; 1.0898x over previous
//
#include <hip/hip_runtime.h>
#include <hip/hip_bf16.h>

// ---------------------------------------------------------------------------
// R3: attention restructure for memory-level parallelism.
//   R2 profile: attn 67us each, 2.5TB/s L2-miss, VALUBusy 33% -> latency
//   chains suspected. Now: 2 waves/node (odd/even edges) x 2-deep unroll
//   = 4 independent gather chains per node; LDS lane-wise combine.
//   K/V interleaved as kv[node][512] (GEMM epilogue writes strided).
// ---------------------------------------------------------------------------

#define DEVFN static __device__ __forceinline__

typedef __attribute__((ext_vector_type(4))) float f32x4;
typedef __attribute__((ext_vector_type(8))) short bf16x8;

DEVFN float bfu2f(unsigned short u) {
    union { unsigned int i; float f; } t; t.i = ((unsigned)u) << 16; return t.f;
}
DEVFN float4 ldb4(const __hip_bfloat16* p) {
    ushort4 u = *reinterpret_cast<const ushort4*>(p);
    return make_float4(bfu2f(u.x), bfu2f(u.y), bfu2f(u.z), bfu2f(u.w));
}
DEVFN unsigned short f2bu(float f) {
    __hip_bfloat16 b = __float2bfloat16(f);
    return __builtin_bit_cast(unsigned short, b);
}
DEVFN void stb4(__hip_bfloat16* p, float4 v) {
    ushort4 u;
    u.x = f2bu(v.x); u.y = f2bu(v.y); u.z = f2bu(v.z); u.w = f2bu(v.w);
    *reinterpret_cast<ushort4*>(p) = u;
}

// --------------------------- converts ---------------------------------------
__global__ __launch_bounds__(256)
void f2b_kernel(const float* __restrict__ in, __hip_bfloat16* __restrict__ out, int n4)
{
    const int i = blockIdx.x * 256 + threadIdx.x;
    if (i >= n4) return;
    const float4 v = *reinterpret_cast<const float4*>(in + (size_t)i * 4);
    stb4(out + (size_t)i * 4, v);
}

// transpose+convert weights: W[k][c] f32 -> Wt[z][c][k] bf16
__global__ __launch_bounds__(256)
void wconv_kernel(const float* __restrict__ W0, const float* __restrict__ W1,
                  const float* __restrict__ W2, const float* __restrict__ W3,
                  const float* __restrict__ W4, const float* __restrict__ W5,
                  const float* __restrict__ W6, const float* __restrict__ W7,
                  __hip_bfloat16* __restrict__ Wt)
{
    const float* W;
    switch (blockIdx.y) {
        case 0: W = W0; break; case 1: W = W1; break;
        case 2: W = W2; break; case 3: W = W3; break;
        case 4: W = W4; break; case 5: W = W5; break;
        case 6: W = W6; break; default: W = W7; break;
    }
    const int k = blockIdx.x;      // 0..255
    const int c = threadIdx.x;     // 0..255
    Wt[(size_t)blockIdx.y * 65536 + (size_t)c * 256 + k] =
        __float2bfloat16(W[(size_t)k * 256 + c]);
}

// ------------------------- GEMM: O[z] = A @ W[z] + b[z] ---------------------
// Per-output row stride rs[z] lets K,V interleave into kv[node][512].
#define SWZ(r, kb) ((r) * 256 + ((kb) ^ (((r) & 7) << 4)))

__global__ __launch_bounds__(256)
void gemm_mfma_kernel(const __hip_bfloat16* __restrict__ A, int M,
                      const __hip_bfloat16* __restrict__ Wt,
                      const float* __restrict__ b0, const float* __restrict__ b1,
                      const float* __restrict__ b2, const float* __restrict__ b3,
                      __hip_bfloat16* __restrict__ O0, __hip_bfloat16* __restrict__ O1,
                      __hip_bfloat16* __restrict__ O2, __hip_bfloat16* __restrict__ O3,
                      int s0, int s1, int s2, int s3)
{
    const int z = blockIdx.z;
    const float* bias; __hip_bfloat16* O; int rs;
    switch (z) {
        case 0:  bias = b0; O = O0; rs = s0; break;
        case 1:  bias = b1; O = O1; rs = s1; break;
        case 2:  bias = b2; O = O2; rs = s2; break;
        default: bias = b3; O = O3; rs = s3; break;
    }
    const __hip_bfloat16* Wz = Wt + (size_t)z * 65536;

    __shared__ char As[128 * 256];
    __shared__ char Bs[128 * 256];

    const int tid  = threadIdx.x;
    const int row0 = blockIdx.x * 128;
    const int col0 = blockIdx.y * 128;
    const int wid  = tid >> 6, lane = tid & 63;
    const int wr   = wid >> 1, wc = wid & 1;
    const int lrow = lane & 15, kg = lane >> 4;

    const int chunk = tid & 15;
    const int rsub  = tid >> 4;

    f32x4 acc[4][4] = {};

    for (int k0 = 0; k0 < 256; k0 += 128) {
        #pragma unroll
        for (int p = 0; p < 8; ++p) {
            const int r  = p * 16 + rsub;
            const int gr = row0 + r;
            ulonglong2 av = {0ull, 0ull};
            if (gr < M)
                av = *reinterpret_cast<const ulonglong2*>(A + (size_t)gr * 256 + k0 + chunk * 8);
            *reinterpret_cast<ulonglong2*>(As + SWZ(r, chunk * 16)) = av;

            const ulonglong2 bv = *reinterpret_cast<const ulonglong2*>(
                Wz + (size_t)(col0 + r) * 256 + k0 + chunk * 8);
            *reinterpret_cast<ulonglong2*>(Bs + SWZ(r, chunk * 16)) = bv;
        }
        __syncthreads();

        #pragma unroll
        for (int kk = 0; kk < 128; kk += 32) {
            const int kbyte = kk * 2 + kg * 16;
            bf16x8 af[4], bfr[4];
            #pragma unroll
            for (int m = 0; m < 4; ++m) {
                const int r = wr * 64 + m * 16 + lrow;
                af[m] = *reinterpret_cast<const bf16x8*>(As + SWZ(r, kbyte));
            }
            #pragma unroll
            for (int n = 0; n < 4; ++n) {
                const int c = wc * 64 + n * 16 + lrow;
                bfr[n] = *reinterpret_cast<const bf16x8*>(Bs + SWZ(c, kbyte));
            }
            #pragma unroll
            for (int m = 0; m < 4; ++m)
                #pragma unroll
                for (int n = 0; n < 4; ++n)
                    acc[m][n] = __builtin_amdgcn_mfma_f32_16x16x32_bf16(
                        af[m], bfr[n], acc[m][n], 0, 0, 0);
        }
        __syncthreads();
    }

    #pragma unroll
    for (int m = 0; m < 4; ++m) {
        #pragma unroll
        for (int j = 0; j < 4; ++j) {
            const int grow = row0 + wr * 64 + m * 16 + kg * 4 + j;
            if (grow >= M) continue;
            #pragma unroll
            for (int n = 0; n < 4; ++n) {
                const int gcol = col0 + wc * 64 + n * 16 + lrow;
                const float v = acc[m][n][j] + bias[gcol];
                O[(size_t)grow * rs + gcol] = __float2bfloat16(v);
            }
        }
    }
}

// ------------------------------ CSR build ----------------------------------
__global__ __launch_bounds__(256)
void hist_kernel(const int* __restrict__ ei, int E, int* __restrict__ deg)
{
    const int e = blockIdx.x * 256 + threadIdx.x;
    if (e < E) atomicAdd(&deg[ei[E + e]], 1);
}

__global__ __launch_bounds__(256)
void gcount_kernel(const int* __restrict__ batch, int N, int* __restrict__ gcount)
{
    __shared__ int h[16];
    if (threadIdx.x < 16) h[threadIdx.x] = 0;
    __syncthreads();
    const int n = blockIdx.x * 256 + threadIdx.x;
    if (n < N) atomicAdd(&h[batch[n]], 1);
    __syncthreads();
    if (threadIdx.x < 16 && h[threadIdx.x] != 0)
        atomicAdd(&gcount[threadIdx.x], h[threadIdx.x]);
}

__global__ __launch_bounds__(64)
void gstart_kernel(const int* __restrict__ gcount, int* __restrict__ gstart)
{
    if (threadIdx.x == 0) {
        int o = 0;
        for (int g = 0; g < 16; ++g) { gstart[g] = o; o += gcount[g]; }
        gstart[16] = o;
    }
}

__global__ __launch_bounds__(1024)
void scan_kernel(const int* __restrict__ deg, int* __restrict__ row_start, int n)
{
    __shared__ int wsum[16];
    __shared__ int wincl[16];
    const int tid  = threadIdx.x;
    const int w    = tid >> 6;
    const int lane = tid & 63;
    if (tid == 0) row_start[0] = 0;
    int offset = 0;
    for (int base = 0; base < n; base += 1024) {
        const int idx = base + tid;
        int s = (idx < n) ? deg[idx] : 0;
        #pragma unroll
        for (int d = 1; d < 64; d <<= 1) {
            const int t = __shfl_up(s, d, 64);
            if (lane >= d) s += t;
        }
        if (lane == 63) wsum[w] = s;
        __syncthreads();
        if (tid < 16) {
            int si = wsum[tid];
            #pragma unroll
            for (int d = 1; d < 16; d <<= 1) {
                const int u = __shfl_up(si, d, 64);
                if (tid >= d) si += u;
            }
            wincl[tid] = si;
        }
        __syncthreads();
        const int woff = (w > 0) ? wincl[w - 1] : 0;
        if (idx < n) row_start[idx + 1] = offset + woff + s;
        offset += wincl[15];
        __syncthreads();
    }
}

__global__ __launch_bounds__(256)
void fill_kernel(const int* __restrict__ ei, int E,
                 const int* __restrict__ row_start,
                 int* __restrict__ cursor, int* __restrict__ csr_src)
{
    const int e = blockIdx.x * 256 + threadIdx.x;
    if (e >= E) return;
    const int s = ei[e];
    const int d = ei[E + e];
    const int pos = atomicAdd(&cursor[d], 1);
    csr_src[row_start[d] + pos] = s;
}

// --------------------- fused attention + gate + layernorm ------------------
// 512 threads = 8 waves = 4 nodes x 2 waves. Each wave: every-other edge,
// 2-deep unroll -> 4 independent gather chains per node. LDS combine.
template <int HL, bool RELU, bool OUTB>
__global__ __launch_bounds__(512)
void attn_kernel(const __hip_bfloat16* __restrict__ Q,
                 const __hip_bfloat16* __restrict__ KV,
                 const __hip_bfloat16* __restrict__ R,
                 const float* __restrict__ Wb, const float* __restrict__ lng,
                 const float* __restrict__ lnb,
                 const int* __restrict__ row_start, const int* __restrict__ csr_src,
                 __hip_bfloat16* __restrict__ outb, float* __restrict__ outf,
                 int N, float scale)
{
    __shared__ float4 sAcc[4][64];
    __shared__ float  sSum[4][64];

    const int w    = threadIdx.x >> 6;     // 0..7
    const int lane = threadIdx.x & 63;
    const int slot = w >> 1;               // 0..3
    const int half = w & 1;
    const int node = blockIdx.x * 4 + slot;
    const bool active = node < N;

    const int d4 = lane * 4;
    float4 q4 = make_float4(0.f, 0.f, 0.f, 0.f);
    int beg = 0, end = 0;
    if (active) {
        q4  = ldb4(Q + (size_t)node * 256 + d4);
        beg = row_start[node];
        end = row_start[node + 1];
    }

    float4 acc0 = make_float4(0.f, 0.f, 0.f, 0.f);
    float4 acc1 = make_float4(0.f, 0.f, 0.f, 0.f);
    float  ssum0 = 0.f, ssum1 = 0.f;

    int i = beg + half;
    for (; i + 2 < end; i += 4) {
        const int sa = csr_src[i];
        const int sb = csr_src[i + 2];
        const float4 ka = ldb4(KV + (size_t)sa * 512 + d4);
        const float4 va = ldb4(KV + (size_t)sa * 512 + 256 + d4);
        const float4 kb = ldb4(KV + (size_t)sb * 512 + d4);
        const float4 vb = ldb4(KV + (size_t)sb * 512 + 256 + d4);
        float pa = q4.x * ka.x + q4.y * ka.y + q4.z * ka.z + q4.w * ka.w;
        float pb = q4.x * kb.x + q4.y * kb.y + q4.z * kb.z + q4.w * kb.w;
        #pragma unroll
        for (int m = 1; m < HL; m <<= 1) {
            pa += __shfl_xor(pa, m, 64);
            pb += __shfl_xor(pb, m, 64);
        }
        const float aa = __expf(pa * scale);
        const float ab = __expf(pb * scale);
        ssum0 += aa; ssum1 += ab;
        acc0.x = fmaf(aa, va.x, acc0.x); acc0.y = fmaf(aa, va.y, acc0.y);
        acc0.z = fmaf(aa, va.z, acc0.z); acc0.w = fmaf(aa, va.w, acc0.w);
        acc1.x = fmaf(ab, vb.x, acc1.x); acc1.y = fmaf(ab, vb.y, acc1.y);
        acc1.z = fmaf(ab, vb.z, acc1.z); acc1.w = fmaf(ab, vb.w, acc1.w);
    }
    if (i < end) {
        const int sa = csr_src[i];
        const float4 ka = ldb4(KV + (size_t)sa * 512 + d4);
        const float4 va = ldb4(KV + (size_t)sa * 512 + 256 + d4);
        float pa = q4.x * ka.x + q4.y * ka.y + q4.z * ka.z + q4.w * ka.w;
        #pragma unroll
        for (int m = 1; m < HL; m <<= 1) pa += __shfl_xor(pa, m, 64);
        const float aa = __expf(pa * scale);
        ssum0 += aa;
        acc0.x = fmaf(aa, va.x, acc0.x); acc0.y = fmaf(aa, va.y, acc0.y);
        acc0.z = fmaf(aa, va.z, acc0.z); acc0.w = fmaf(aa, va.w, acc0.w);
    }

    float4 acc = make_float4(acc0.x + acc1.x, acc0.y + acc1.y,
                             acc0.z + acc1.z, acc0.w + acc1.w);
    float ssum = ssum0 + ssum1;

    if (half == 1) {
        sAcc[slot][lane] = acc;
        sSum[slot][lane] = ssum;
    }
    __syncthreads();
    if (half == 1 || !active) return;

    const float4 oa = sAcc[slot][lane];
    acc.x += oa.x; acc.y += oa.y; acc.z += oa.z; acc.w += oa.w;
    ssum += sSum[slot][lane];

    float4 o4 = make_float4(0.f, 0.f, 0.f, 0.f);
    if (ssum > 0.f) {
        const float is = 1.f / ssum;
        o4.x = acc.x * is; o4.y = acc.y * is; o4.z = acc.z * is; o4.w = acc.w * is;
    }

    const float4 r4  = ldb4(R + (size_t)node * 256 + d4);
    const float4 wb0 = *reinterpret_cast<const float4*>(Wb + d4);
    const float4 wb1 = *reinterpret_cast<const float4*>(Wb + 256 + d4);
    const float4 wb2 = *reinterpret_cast<const float4*>(Wb + 512 + d4);
    float z = o4.x * wb0.x + o4.y * wb0.y + o4.z * wb0.z + o4.w * wb0.w
            + r4.x * wb1.x + r4.y * wb1.y + r4.z * wb1.z + r4.w * wb1.w
            + (o4.x - r4.x) * wb2.x + (o4.y - r4.y) * wb2.y
            + (o4.z - r4.z) * wb2.z + (o4.w - r4.w) * wb2.w;
    #pragma unroll
    for (int m = 1; m < 64; m <<= 1) z += __shfl_xor(z, m, 64);
    const float g = 1.f / (1.f + __expf(-z));

    float4 h4;
    h4.x = g * r4.x + (1.f - g) * o4.x;
    h4.y = g * r4.y + (1.f - g) * o4.y;
    h4.z = g * r4.z + (1.f - g) * o4.z;
    h4.w = g * r4.w + (1.f - g) * o4.w;

    float s1 = h4.x + h4.y + h4.z + h4.w;
    float s2 = h4.x * h4.x + h4.y * h4.y + h4.z * h4.z + h4.w * h4.w;
    #pragma unroll
    for (int m = 1; m < 64; m <<= 1) {
        s1 += __shfl_xor(s1, m, 64);
        s2 += __shfl_xor(s2, m, 64);
    }
    const float mu  = s1 * (1.f / 256.f);
    const float var = s2 * (1.f / 256.f) - mu * mu;
    const float inv = rsqrtf(var + 1e-5f);

    const float4 ga = *reinterpret_cast<const float4*>(lng + d4);
    const float4 be = *reinterpret_cast<const float4*>(lnb + d4);
    h4.x = (h4.x - mu) * inv * ga.x + be.x;
    h4.y = (h4.y - mu) * inv * ga.y + be.y;
    h4.z = (h4.z - mu) * inv * ga.z + be.z;
    h4.w = (h4.w - mu) * inv * ga.w + be.w;

    if (RELU) {
        h4.x = fmaxf(h4.x, 0.f);
        h4.y = fmaxf(h4.y, 0.f);
        h4.z = fmaxf(h4.z, 0.f);
        h4.w = fmaxf(h4.w, 0.f);
    }

    if (OUTB) stb4(outb + (size_t)node * 256 + d4, h4);
    else      *reinterpret_cast<float4*>(outf + (size_t)node * 256 + d4) = h4;
}

// ------------------------------ mean pool (two-stage) ----------------------
__global__ __launch_bounds__(256)
void pool_partial_kernel(const float* __restrict__ h, const int* __restrict__ gstart,
                         float* __restrict__ partial)
{
    const int s    = blockIdx.x;
    const int g    = blockIdx.y;
    const int tid  = threadIdx.x;
    const int quad = tid & 63;
    const int sub  = tid >> 6;

    const int beg = gstart[g];
    const int cnt = gstart[g + 1] - beg;

    f32x4 acc = {0.f, 0.f, 0.f, 0.f};
    for (int i = s * 4 + sub; i < cnt; i += 64) {
        const f32x4 v = *reinterpret_cast<const f32x4*>(
            h + (size_t)(beg + i) * 256 + quad * 4);
        acc += v;
    }

    __shared__ f32x4 sh[4][64];
    sh[sub][quad] = acc;
    __syncthreads();
    if (sub == 0) {
        const f32x4 r = sh[0][quad] + sh[1][quad] + sh[2][quad] + sh[3][quad];
        *reinterpret_cast<f32x4*>(partial + ((size_t)(g * 16 + s) * 64 + quad) * 4) = r;
    }
}

__global__ __launch_bounds__(256)
void pool_final_kernel(const float* __restrict__ partial, const int* __restrict__ gcount,
                       float* __restrict__ out)
{
    const int g = blockIdx.x;
    const int d = threadIdx.x;
    float sum = 0.f;
    #pragma unroll
    for (int s = 0; s < 16; ++s)
        sum += partial[(size_t)(g * 16 + s) * 256 + d];
    out[(size_t)g * 256 + d] = sum / (float)max(gcount[g], 1);
}

// ------------------------------- launcher ----------------------------------
extern "C" void kernel_launch(void* const* d_in, const int* in_sizes, int n_in,
                              void* d_out, int out_size, void* d_ws, size_t ws_size,
                              hipStream_t stream)
{
    const float* x     = (const float*)d_in[0];
    const int*   ei    = (const int*)d_in[1];
    const int*   batch = (const int*)d_in[2];
    const float* Wq0 = (const float*)d_in[3];  const float* bq0 = (const float*)d_in[4];
    const float* Wk0 = (const float*)d_in[5];  const float* bk0 = (const float*)d_in[6];
    const float* Wv0 = (const float*)d_in[7];  const float* bv0 = (const float*)d_in[8];
    const float* Ws0 = (const float*)d_in[9];  const float* bs0 = (const float*)d_in[10];
    const float* Wb0 = (const float*)d_in[11];
    const float* g0  = (const float*)d_in[12]; const float* b0  = (const float*)d_in[13];
    const float* Wq1 = (const float*)d_in[14]; const float* bq1 = (const float*)d_in[15];
    const float* Wk1 = (const float*)d_in[16]; const float* bk1 = (const float*)d_in[17];
    const float* Wv1 = (const float*)d_in[18]; const float* bv1 = (const float*)d_in[19];
    const float* Ws1 = (const float*)d_in[20]; const float* bs1 = (const float*)d_in[21];
    const float* Wb1 = (const float*)d_in[22];
    const float* g1  = (const float*)d_in[23]; const float* b1  = (const float*)d_in[24];

    const int N = in_sizes[0] / 256;
    const int E = in_sizes[1] / 2;
    const int G = 16;
    const size_t NM = (size_t)N * 256;

    __hip_bfloat16* bws = (__hip_bfloat16*)d_ws;
    __hip_bfloat16* xb  = bws;
    __hip_bfloat16* qb  = xb  + NM;
    __hip_bfloat16* kvb = qb  + NM;               // [N][512] interleaved K|V
    __hip_bfloat16* rb  = kvb + 2 * NM;
    __hip_bfloat16* h0b = rb  + NM;
    __hip_bfloat16* wt  = h0b + NM;               // 8 * 65536 bf16
    float* h1f     = (float*)(wt + 8 * 65536);
    float* partial = h1f + NM;                    // 16*16*256 f32
    int* deg       = (int*)(partial + 16 * 16 * 256);
    int* row_start = deg + N;
    int* cursor    = row_start + N + 1;
    int* gcount    = cursor + N;
    int* gstart    = gcount + G;                  // 17
    int* csr_src   = gstart + 17;

    const size_t zbytes = ((size_t)N + (N + 1) + N + G + 17) * sizeof(int);
    hipMemsetAsync(deg, 0, zbytes, stream);

    const int eb = (E + 255) / 256;
    const int nb = (N + 255) / 256;

    f2b_kernel<<<(int)((NM / 4 + 255) / 256), 256, 0, stream>>>(x, xb, (int)(NM / 4));
    wconv_kernel<<<dim3(256, 8), 256, 0, stream>>>(Wq0, Wk0, Wv0, Ws0,
                                                   Wq1, Wk1, Wv1, Ws1, wt);

    hist_kernel<<<eb, 256, 0, stream>>>(ei, E, deg);
    gcount_kernel<<<nb, 256, 0, stream>>>(batch, N, gcount);
    gstart_kernel<<<1, 64, 0, stream>>>(gcount, gstart);
    scan_kernel<<<1, 1024, 0, stream>>>(deg, row_start, N);
    fill_kernel<<<eb, 256, 0, stream>>>(ei, E, row_start, cursor, csr_src);

    const dim3 ggrid((N + 127) / 128, 2, 4);
    const int  agrid = (N + 3) / 4;

    gemm_mfma_kernel<<<ggrid, 256, 0, stream>>>(xb, N, wt,
        bq0, bk0, bv0, bs0, qb, kvb, kvb + 256, rb, 256, 512, 512, 256);
    attn_kernel<16, true, true><<<agrid, 512, 0, stream>>>(
        qb, kvb, rb, Wb0, g0, b0, row_start, csr_src, h0b, nullptr, N, 0.125f);

    gemm_mfma_kernel<<<ggrid, 256, 0, stream>>>(h0b, N, wt + 4 * 65536,
        bq1, bk1, bv1, bs1, qb, kvb, kvb + 256, rb, 256, 512, 512, 256);
    attn_kernel<64, false, false><<<agrid, 512, 0, stream>>>(
        qb, kvb, rb, Wb1, g1, b1, row_start, csr_src, nullptr, h1f, N, 0.0625f);

    pool_partial_kernel<<<dim3(16, 16), 256, 0, stream>>>(h1f, gstart, partial);
    pool_final_kernel<<<16, 256, 0, stream>>>(partial, gcount, (float*)d_out);
}